// Round 1
// baseline (9605.199 us; speedup 1.0000x reference)
//
#include <hip/hip_runtime.h>

// MetaLSTMDetector: 2-layer LSTM (H=256) over T=4096, B=64, then [2]-dim head.
//
// Design: 32 teams x 8 blocks (256 blocks, 1/CU, 512 thr). Each team owns 2
// batch sequences. Weights are converted to bf16 and held in VGPRs as MFMA
// A-fragments (192KB/block). Per step, each wave computes one 16-row gate
// tile per layer with mfma_f32_16x16x32_bf16 (batches in the N dim,
// duplicated across columns). h0/h1 slices are exchanged team-wide through
// L3 via relaxed agent-scope 32-bit atomics + per-block step flags.
// Layer1 trails layer0 by 1 step; output head trails by 2 -> ONE exchange/step.

#define T_LEN 4096
#define HID 256
#define NTEAM 32
#define TEAM_STRIDE 8192  // bytes of workspace per team

typedef float  f32x4  __attribute__((ext_vector_type(4)));
typedef short  bf16x8 __attribute__((ext_vector_type(8)));
typedef short  short4v __attribute__((ext_vector_type(4)));

__device__ __forceinline__ unsigned int f2bf(float f) {
    unsigned int u = __float_as_uint(f);
    u += 0x7fffu + ((u >> 16) & 1u);   // RNE
    return u >> 16;
}
__device__ __forceinline__ float bf2f(unsigned short h) {
    return __uint_as_float(((unsigned int)h) << 16);
}
__device__ __forceinline__ float sigm(float x) { return 1.0f / (1.0f + __expf(-x)); }
__device__ __forceinline__ float tanhfast(float x) { return 2.0f / (1.0f + __expf(-2.0f * x)) - 1.0f; }

// Zero team workspace (flags + h exchange buffers). d_ws is poisoned 0xAA
// before every launch, so this must run first each launch.
__global__ void init_ws_kernel(unsigned int* ws) {
    int i = blockIdx.x * blockDim.x + threadIdx.x;
    if (i < NTEAM * TEAM_STRIDE / 4) ws[i] = 0u;
}

__global__ __launch_bounds__(512, 2) void lstm_kernel(
    const float* __restrict__ y,
    const float* __restrict__ Wih0, const float* __restrict__ Whh0,
    const float* __restrict__ bih0, const float* __restrict__ bhh0,
    const float* __restrict__ Wih1, const float* __restrict__ Whh1,
    const float* __restrict__ bih1, const float* __restrict__ bhh1,
    const float* __restrict__ Wout, const float* __restrict__ bout,
    float* __restrict__ out, char* __restrict__ ws)
{
    const int tid = threadIdx.x;
    const int bid = blockIdx.x;
    const int tm  = bid & 31;   // team; bid = m*32+tm so team members share an XCD if XCD==bid%8
    const int m   = bid >> 5;   // team member 0..7
    const int w   = tid >> 6;   // wave 0..7
    const int l   = tid & 63;   // lane
    const int col = l & 15;     // MFMA column (batch, duplicated)
    const int bc  = col & 1;    // batch within team
    const int kg  = l >> 4;     // k-group / C-row group

    __shared__ __attribute__((aligned(16))) float          yl[2][T_LEN + 4];
    __shared__ __attribute__((aligned(16))) unsigned short h0l[2][HID];
    __shared__ __attribute__((aligned(16))) unsigned short h1l[2][HID];

    char* tb = ws + (size_t)tm * TEAM_STRIDE;
    int*          flags = (int*)tb;                        // [8] used
    unsigned int* h0g   = (unsigned int*)(tb + 128);       // [2 slots][256] (lo=batch0,hi=batch1)
    unsigned int* h1g   = (unsigned int*)(tb + 128 + 2048);

    // ---- stage y (shifted by 3 with -100 front pad) and zero h state ----
    for (int b = 0; b < 2; ++b) {
        const float* src = y + (size_t)(tm * 2 + b) * T_LEN;
        for (int i = tid; i < T_LEN; i += 512) yl[b][3 + i] = src[i];
    }
    if (tid < 3) { yl[0][tid] = -100.0f; yl[1][tid] = -100.0f; }
    for (int i = tid; i < 2 * HID; i += 512) {
        ((unsigned short*)h0l)[i] = 0; ((unsigned short*)h1l)[i] = 0;
    }

    // ---- load weight A-fragments (bf16) ----
    // A-tile row tr = col (0..15) = unit_local(tr>>2)*4 + gate(tr&3)
    const int tr   = col;
    const int urow = m * 32 + w * 4 + (tr >> 2);
    const int R    = (tr & 3) * HID + urow;        // row in [4H] gate-major order (i,f,g,o)

    bf16x8 a0[8], a1[16];
    {
        const float* w0 = Whh0 + (size_t)R * HID;
        #pragma unroll
        for (int kf = 0; kf < 8; ++kf) {
            bf16x8 v;
            #pragma unroll
            for (int i = 0; i < 8; ++i) v[i] = (short)f2bf(w0[kf * 32 + kg * 8 + i]);
            a0[kf] = v;
        }
        const float* w1 = Wih1 + (size_t)R * HID;
        #pragma unroll
        for (int kf = 0; kf < 8; ++kf) {
            bf16x8 v;
            #pragma unroll
            for (int i = 0; i < 8; ++i) v[i] = (short)f2bf(w1[kf * 32 + kg * 8 + i]);
            a1[kf] = v;
        }
        const float* w2 = Whh1 + (size_t)R * HID;
        #pragma unroll
        for (int kf = 0; kf < 8; ++kf) {
            bf16x8 v;
            #pragma unroll
            for (int i = 0; i < 8; ++i) v[i] = (short)f2bf(w2[kf * 32 + kg * 8 + i]);
            a1[8 + kf] = v;
        }
    }

    // C-rows for this lane: rows kg*4+i -> unit U=(base+kg), gate i
    const int U = m * 32 + w * 4 + kg;
    float bias0[4], bias1[4], wx[4][4];
    #pragma unroll
    for (int i = 0; i < 4; ++i) {
        int r = i * HID + U;
        bias0[i] = bih0[r] + bhh0[r];
        bias1[i] = bih1[r] + bhh1[r];
        #pragma unroll
        for (int j = 0; j < 4; ++j) wx[i][j] = Wih0[r * 4 + j];
    }
    float wo0[4], wo1[4];
    #pragma unroll
    for (int j = 0; j < 4; ++j) { wo0[j] = Wout[l * 4 + j]; wo1[j] = Wout[HID + l * 4 + j]; }
    const float bo0 = bout[0], bo1 = bout[1];

    float c0 = 0.0f, c1 = 0.0f;
    __syncthreads();

    // ---- main recurrence ----
    for (int s = 0; s <= T_LEN + 1; ++s) {
        const int slot = s & 1;
        const bf16x8* hb0 = (const bf16x8*)(&h0l[bc][0]);  // h0[s-1]
        const bf16x8* hb1 = (const bf16x8*)(&h1l[bc][0]);  // h1[s-2]

        // ---- layer 0, step s ----
        if (s < T_LEN) {
            float x0 = yl[bc][s], x1 = yl[bc][s + 1], x2 = yl[bc][s + 2], x3 = yl[bc][s + 3];
            f32x4 acc, accb;
            #pragma unroll
            for (int i = 0; i < 4; ++i) {
                acc[i] = bias0[i] + x0 * wx[i][0] + x1 * wx[i][1] + x2 * wx[i][2] + x3 * wx[i][3];
                accb[i] = 0.0f;
            }
            #pragma unroll
            for (int kf = 0; kf < 4; ++kf)
                acc = __builtin_amdgcn_mfma_f32_16x16x32_bf16(a0[kf], hb0[kf * 4 + kg], acc, 0, 0, 0);
            #pragma unroll
            for (int kf = 4; kf < 8; ++kf)
                accb = __builtin_amdgcn_mfma_f32_16x16x32_bf16(a0[kf], hb0[kf * 4 + kg], accb, 0, 0, 0);
            float gi = acc[0] + accb[0], gf = acc[1] + accb[1];
            float gg = acc[2] + accb[2], go = acc[3] + accb[3];
            c0 = sigm(gf) * c0 + sigm(gi) * tanhfast(gg);
            float h0n = sigm(go) * tanhfast(c0);
            unsigned int hv = f2bf(h0n);
            unsigned int hh = __shfl_down(hv, 1, 64);      // batch1 value into col0 lane
            if (col == 0)
                __hip_atomic_store(&h0g[slot * HID + U], (hv & 0xffffu) | (hh << 16),
                                   __ATOMIC_RELAXED, __HIP_MEMORY_SCOPE_AGENT);
        }

        // ---- layer 1, step s-1 ----
        if (s >= 1 && s <= T_LEN) {
            f32x4 acc, accb;
            #pragma unroll
            for (int i = 0; i < 4; ++i) { acc[i] = bias1[i]; accb[i] = 0.0f; }
            #pragma unroll
            for (int kf = 0; kf < 4; ++kf)
                acc = __builtin_amdgcn_mfma_f32_16x16x32_bf16(a1[kf], hb0[kf * 4 + kg], acc, 0, 0, 0);
            #pragma unroll
            for (int kf = 4; kf < 8; ++kf)
                accb = __builtin_amdgcn_mfma_f32_16x16x32_bf16(a1[kf], hb0[kf * 4 + kg], accb, 0, 0, 0);
            #pragma unroll
            for (int kf = 0; kf < 4; ++kf)
                acc = __builtin_amdgcn_mfma_f32_16x16x32_bf16(a1[8 + kf], hb1[kf * 4 + kg], acc, 0, 0, 0);
            #pragma unroll
            for (int kf = 4; kf < 8; ++kf)
                accb = __builtin_amdgcn_mfma_f32_16x16x32_bf16(a1[8 + kf], hb1[kf * 4 + kg], accb, 0, 0, 0);
            float gi = acc[0] + accb[0], gf = acc[1] + accb[1];
            float gg = acc[2] + accb[2], go = acc[3] + accb[3];
            c1 = sigm(gf) * c1 + sigm(gi) * tanhfast(gg);
            float h1n = sigm(go) * tanhfast(c1);
            unsigned int hv = f2bf(h1n);
            unsigned int hh = __shfl_down(hv, 1, 64);
            if (col == 0)
                __hip_atomic_store(&h1g[slot * HID + U], (hv & 0xffffu) | (hh << 16),
                                   __ATOMIC_RELAXED, __HIP_MEMORY_SCOPE_AGENT);
        }

        // ---- output head, step s-2 (one block's wave 0 per team) ----
        if (m == 0 && w == 0 && s >= 2) {
            float p00 = 0, p01 = 0, p10 = 0, p11 = 0;
            #pragma unroll
            for (int j = 0; j < 4; ++j) {
                float hv0 = bf2f(h1l[0][l * 4 + j]);
                float hv1 = bf2f(h1l[1][l * 4 + j]);
                p00 += hv0 * wo0[j]; p01 += hv0 * wo1[j];
                p10 += hv1 * wo0[j]; p11 += hv1 * wo1[j];
            }
            #pragma unroll
            for (int off = 32; off >= 1; off >>= 1) {
                p00 += __shfl_xor(p00, off, 64);
                p01 += __shfl_xor(p01, off, 64);
                p10 += __shfl_xor(p10, off, 64);
                p11 += __shfl_xor(p11, off, 64);
            }
            if (l == 0) {
                int t = s - 2;
                float* o0 = out + ((size_t)(tm * 2 + 0) * T_LEN + t) * 2;
                float* o1 = out + ((size_t)(tm * 2 + 1) * T_LEN + t) * 2;
                o0[0] = p00 + bo0; o0[1] = p01 + bo1;
                o1[0] = p10 + bo0; o1[1] = p11 + bo1;
            }
        }

        __syncthreads();  // drains all vmem (publish stores complete at coherence point)
        if (tid == 0)
            __hip_atomic_store(&flags[m], s + 1, __ATOMIC_RELAXED, __HIP_MEMORY_SCOPE_AGENT);

        if (s <= T_LEN) {
            if (w == 0) {          // gather h0[s]
                if (l < 8)
                    while (__hip_atomic_load(&flags[l], __ATOMIC_RELAXED, __HIP_MEMORY_SCOPE_AGENT) < s + 1) {}
                unsigned int v0 = __hip_atomic_load(&h0g[slot * HID + l * 4 + 0], __ATOMIC_RELAXED, __HIP_MEMORY_SCOPE_AGENT);
                unsigned int v1 = __hip_atomic_load(&h0g[slot * HID + l * 4 + 1], __ATOMIC_RELAXED, __HIP_MEMORY_SCOPE_AGENT);
                unsigned int v2 = __hip_atomic_load(&h0g[slot * HID + l * 4 + 2], __ATOMIC_RELAXED, __HIP_MEMORY_SCOPE_AGENT);
                unsigned int v3 = __hip_atomic_load(&h0g[slot * HID + l * 4 + 3], __ATOMIC_RELAXED, __HIP_MEMORY_SCOPE_AGENT);
                short4v r0 = { (short)(v0 & 0xffffu), (short)(v1 & 0xffffu), (short)(v2 & 0xffffu), (short)(v3 & 0xffffu) };
                short4v r1 = { (short)(v0 >> 16),     (short)(v1 >> 16),     (short)(v2 >> 16),     (short)(v3 >> 16) };
                *(short4v*)&h0l[0][l * 4] = r0;
                *(short4v*)&h0l[1][l * 4] = r1;
            } else if (w == 1) {   // gather h1[s-1]
                if (l < 8)
                    while (__hip_atomic_load(&flags[l], __ATOMIC_RELAXED, __HIP_MEMORY_SCOPE_AGENT) < s + 1) {}
                unsigned int v0 = __hip_atomic_load(&h1g[slot * HID + l * 4 + 0], __ATOMIC_RELAXED, __HIP_MEMORY_SCOPE_AGENT);
                unsigned int v1 = __hip_atomic_load(&h1g[slot * HID + l * 4 + 1], __ATOMIC_RELAXED, __HIP_MEMORY_SCOPE_AGENT);
                unsigned int v2 = __hip_atomic_load(&h1g[slot * HID + l * 4 + 2], __ATOMIC_RELAXED, __HIP_MEMORY_SCOPE_AGENT);
                unsigned int v3 = __hip_atomic_load(&h1g[slot * HID + l * 4 + 3], __ATOMIC_RELAXED, __HIP_MEMORY_SCOPE_AGENT);
                short4v r0 = { (short)(v0 & 0xffffu), (short)(v1 & 0xffffu), (short)(v2 & 0xffffu), (short)(v3 & 0xffffu) };
                short4v r1 = { (short)(v0 >> 16),     (short)(v1 >> 16),     (short)(v2 >> 16),     (short)(v3 >> 16) };
                *(short4v*)&h1l[0][l * 4] = r0;
                *(short4v*)&h1l[1][l * 4] = r1;
            }
        }
        __syncthreads();
    }
}

extern "C" void kernel_launch(void* const* d_in, const int* in_sizes, int n_in,
                              void* d_out, int out_size, void* d_ws, size_t ws_size,
                              hipStream_t stream) {
    const float* y    = (const float*)d_in[0];
    const float* Wih0 = (const float*)d_in[1];
    const float* Whh0 = (const float*)d_in[2];
    const float* bih0 = (const float*)d_in[3];
    const float* bhh0 = (const float*)d_in[4];
    const float* Wih1 = (const float*)d_in[5];
    const float* Whh1 = (const float*)d_in[6];
    const float* bih1 = (const float*)d_in[7];
    const float* bhh1 = (const float*)d_in[8];
    const float* Wout = (const float*)d_in[9];
    const float* bout = (const float*)d_in[10];

    init_ws_kernel<<<dim3(256), dim3(256), 0, stream>>>((unsigned int*)d_ws);
    lstm_kernel<<<dim3(256), dim3(512), 0, stream>>>(
        y, Wih0, Whh0, bih0, bhh0, Wih1, Whh1, bih1, bhh1, Wout, bout,
        (float*)d_out, (char*)d_ws);
}